// Round 9
// baseline (178.065 us; speedup 1.0000x reference)
//
#include <hip/hip_runtime.h>
#include <hip/hip_bf16.h>
#include <hip/hip_fp16.h>

// GAT layer on MI355X (gfx950).
//   x: (N=50000, K=256) fp32, W: (K=256, F=64) fp32, a: (1, 128) fp32
//   edge_index: (2, E=1600000) int (src row 0, dst row 1)
// out = elu( segsum_src(e * h[dst]) / segsum_src(e) ),
//   e = exp(-leakyrelu(s_src[src]+s_dst[dst], 0.2)), h = x@W
//
// Round 19 (ablation): K_A's 52us survived 8 reconfigs; Sum(dispatch) vs
// wall gap (~65us) proved launch-count-invariant -> launches are free.
// Split K_A into gat_bin_kernel + gat_gemm_kernel (byte-identical bodies)
// to get per-path timings and find the real pole. K_B unchanged.

#define ALPHA 0.2f
#define KDIM 256
#define FDIM 64
#define WPAD 8             // bf16 row pad: row stride 264 elems = 528B
#define BIN_CHUNK 8192
#define BUCKET_CAP 4096    // 64-src bucket: mean ~2046 edges; >40 sigma slack
#define HCAP 2304          // 32-src half bucket: mean ~1023; ~40 sigma slack

typedef __bf16 bf16x8 __attribute__((ext_vector_type(8)));
typedef float f32x4 __attribute__((ext_vector_type(4)));
typedef unsigned int u32;
typedef unsigned short u16;

// ---------------------------------------------------------------------------
// Kernel 1: bin. 196 blocks x 256 thr. Local hist over 8192-edge chunk,
// one reservation atomic per (block,bucket) on bcur, packed scatter.
// ---------------------------------------------------------------------------
__global__ __launch_bounds__(256) void gat_bin_kernel(
    const int* __restrict__ srcA, const int* __restrict__ dstA,
    int* __restrict__ bcur, u32* __restrict__ pair,
    int E, int NBU)
{
    __shared__ int hist[1024];
    __shared__ int lcur[1024];
    const int t = threadIdx.x;

    for (int j = t; j < 1024; j += 256) hist[j] = 0;
    __syncthreads();
    const int base = blockIdx.x * BIN_CHUNK;
    const int cnt = min(BIN_CHUNK, E - base);
    for (int i = t; i < cnt; i += 256)
        atomicAdd(&hist[srcA[base + i] >> 6], 1);
    __syncthreads();
    for (int j = t; j < NBU; j += 256) {
        const int v = hist[j];
        lcur[j] = v ? (j * BUCKET_CAP + atomicAdd(&bcur[j], v)) : 0;
    }
    __syncthreads();
    for (int i = t; i < cnt; i += 256) {
        const int s = srcA[base + i];
        const int d = dstA[base + i];
        const int pos = atomicAdd(&lcur[s >> 6], 1);
        pair[pos] = ((u32)(s & 63) << 16) | (u32)d;   // d < 65536
    }
}

// ---------------------------------------------------------------------------
// Kernel 2: gemm. 782 blocks x 256 thr. Per-block W^T in LDS (bf16, padded
// rows), then 1 row-tile (16 rows) per wave via mfma_f32_16x16x32_bf16.
// ---------------------------------------------------------------------------
__global__ __launch_bounds__(256) void gat_gemm_kernel(
    const float* __restrict__ x, const float* __restrict__ W,
    const float* __restrict__ a, __hip_bfloat16* __restrict__ h_bf,
    float* __restrict__ s_src, float* __restrict__ s_dst, int N)
{
    __shared__ __bf16 w[FDIM * (KDIM + WPAD)];
    const int t = threadIdx.x;

    for (int i = t; i < KDIM * FDIM; i += 256) {
        const int k = i >> 6;
        const int n = i & 63;
        w[n * (KDIM + WPAD) + k] = (__bf16)W[i];
    }
    __syncthreads();

    const int gb = (int)blockIdx.x;
    const int lane = t & 63;
    const int wv = t >> 6;              // 0..3
    const int m0 = gb * 64 + wv * 16;   // this wave: rows m0..m0+15
    const int c = lane & 15;
    const int q = lane >> 4;

    const int r0 = m0 + c;
    const float* xp0 = x + (long)(r0 < N ? r0 : N - 1) * KDIM;

    f32x4 acc[4];
#pragma unroll
    for (int ct = 0; ct < 4; ++ct) acc[ct] = (f32x4){0.f, 0.f, 0.f, 0.f};

#pragma unroll 4
    for (int kc = 0; kc < 8; ++kc) {
        const int k0 = kc * 32 + q * 8;
        const float4 xa0 = *(const float4*)(xp0 + k0);
        const float4 xb0 = *(const float4*)(xp0 + k0 + 4);
        bf16x8 af0;
        af0[0] = (__bf16)xa0.x; af0[1] = (__bf16)xa0.y;
        af0[2] = (__bf16)xa0.z; af0[3] = (__bf16)xa0.w;
        af0[4] = (__bf16)xb0.x; af0[5] = (__bf16)xb0.y;
        af0[6] = (__bf16)xb0.z; af0[7] = (__bf16)xb0.w;
#pragma unroll
        for (int ct = 0; ct < 4; ++ct) {
            const bf16x8 bf = *(const bf16x8*)(&w[(ct * 16 + c) * (KDIM + WPAD) + k0]);
            acc[ct] = __builtin_amdgcn_mfma_f32_16x16x32_bf16(af0, bf, acc[ct], 0, 0, 0);
        }
    }

    float a1c[4], a2c[4];
#pragma unroll
    for (int ct = 0; ct < 4; ++ct) {
        a1c[ct] = a[ct * 16 + c];
        a2c[ct] = a[FDIM + ct * 16 + c];
    }

    float s1r[4], s2r[4];
#pragma unroll
    for (int reg = 0; reg < 4; ++reg) {
        float s1 = 0.f, s2 = 0.f;
#pragma unroll
        for (int ct = 0; ct < 4; ++ct) {
            s1 += acc[ct][reg] * a1c[ct];
            s2 += acc[ct][reg] * a2c[ct];
        }
        s1r[reg] = s1; s2r[reg] = s2;
    }
#pragma unroll
    for (int off = 1; off < 16; off <<= 1) {
#pragma unroll
        for (int reg = 0; reg < 4; ++reg) {
            s1r[reg] += __shfl_xor(s1r[reg], off);
            s2r[reg] += __shfl_xor(s2r[reg], off);
        }
    }
#pragma unroll
    for (int reg = 0; reg < 4; ++reg) {
        const int row = m0 + q * 4 + reg;
        if (row < N) {
#pragma unroll
            for (int ct = 0; ct < 4; ++ct)
                h_bf[(long)row * FDIM + ct * 16 + c] = __float2bfloat16(acc[ct][reg]);
            if (c == 0) { s_src[row] = s1r[reg]; s_dst[row] = s2r[reg]; }
        }
    }
}

// ---------------------------------------------------------------------------
// Kernel 3 (fused sort+gather, half-bucket blocks): 2 blocks (256 thr) per
// 64-src bucket; block handles 32 srcs (half = blockIdx&1).
// ---------------------------------------------------------------------------
__global__ __launch_bounds__(256) void gat_sortgather_kernel(
    const u32* __restrict__ pair, const int* __restrict__ bcur,
    const float* __restrict__ s_src, const float* __restrict__ s_dst,
    const __hip_bfloat16* __restrict__ h_bf, float* __restrict__ out, int N)
{
    __shared__ u32 slds[HCAP];   // 9 KB sorted (dst | f16(wgt)<<16)
    __shared__ int cur[32];
    __shared__ int nst[32];
    __shared__ int nen[32];
    __shared__ float ssl[32];

    const int b = (int)blockIdx.x >> 1;    // bucket
    const int hf = (int)blockIdx.x & 1;    // half: srcs [hf*32, hf*32+32)
    const int t = threadIdx.x;
    const int s0 = (b << 6) + (hf << 5);   // first src of this half
    const int abase = b * BUCKET_CAP;
    const int n = min(bcur[b], BUCKET_CAP);

    if (t < 32) {
        cur[t] = 0;
        ssl[t] = (s0 + t < N) ? s_src[s0 + t] : 0.f;
    }
    __syncthreads();
    // pass 1: count srcs belonging to this half
    for (int i = t; i < n; i += 256) {
        const int sl = (int)(pair[abase + i] >> 16);
        if ((sl >> 5) == hf) atomicAdd(&cur[sl & 31], 1);
    }
    __syncthreads();
    if (t < 32) {   // lanes 0..31 of wave 0: exclusive scan of 32 counts
        const int v = cur[t];
        int incl = v;
#pragma unroll
        for (int off = 1; off < 32; off <<= 1) {
            const int nv = __shfl_up(incl, off);
            if (t >= off) incl += nv;
        }
        const int excl = incl - v;
        nst[t] = excl;
        nen[t] = min(excl + v, HCAP);
        cur[t] = excl;
    }
    __syncthreads();
    // pass 2: scatter matching edges into slds with packed weight
    for (int i = t; i < n; i += 256) {
        const u32 p = pair[abase + i];
        const int sl = (int)(p >> 16);
        if ((sl >> 5) != hf) continue;
        const int d = (int)(p & 0xFFFFu);
        const int slot = atomicAdd(&cur[sl & 31], 1);
        if (slot < HCAP) {
            const float sc = ssl[sl & 31] + s_dst[d];
            const float lr = sc > 0.f ? sc : ALPHA * sc;
            const float wgt = __expf(-lr);
            const u32 wh = (u32)__half_as_ushort(__float2half(wgt));
            slds[slot] = (u32)d | (wh << 16);
        }
    }
    __syncthreads();

    // ---------------- phase B: gather from LDS edge list ----------------
    const int wv = t >> 6;       // 0..3
    const int lane = t & 63;
    const int q = lane >> 3;     // edge slot 0..7
    const int c = lane & 7;      // feature octet 0..7
    const __bf16* hb = (const __bf16*)h_bf;

    for (int nl = wv; nl < 32; nl += 4) {
        const int node = s0 + nl;
        if (node >= N) break;
        const int start = nst[nl];
        const int end = nen[nl];

        float acc0[8], acc1[8];
#pragma unroll
        for (int j = 0; j < 8; ++j) { acc0[j] = 0.f; acc1[j] = 0.f; }
        float wsum0 = 0.f, wsum1 = 0.f;

        int e = start + q;
        for (; e + 8 < end; e += 16) {
            const u32 p0 = slds[e];
            const u32 p1 = slds[e + 8];
            const int d0 = (int)(p0 & 0xFFFFu);
            const int d1 = (int)(p1 & 0xFFFFu);
            const bf16x8 hv0 = *(const bf16x8*)(hb + (long)d0 * FDIM + 8 * c);
            const bf16x8 hv1 = *(const bf16x8*)(hb + (long)d1 * FDIM + 8 * c);
            const float w0 = __half2float(__ushort_as_half((u16)(p0 >> 16)));
            const float w1 = __half2float(__ushort_as_half((u16)(p1 >> 16)));
#pragma unroll
            for (int j = 0; j < 8; ++j) {
                acc0[j] += w0 * (float)hv0[j];
                acc1[j] += w1 * (float)hv1[j];
            }
            wsum0 += w0;
            wsum1 += w1;
        }
        if (e < end) {
            const u32 p0 = slds[e];
            const int d0 = (int)(p0 & 0xFFFFu);
            const bf16x8 hv0 = *(const bf16x8*)(hb + (long)d0 * FDIM + 8 * c);
            const float w0 = __half2float(__ushort_as_half((u16)(p0 >> 16)));
#pragma unroll
            for (int j = 0; j < 8; ++j) acc0[j] += w0 * (float)hv0[j];
            wsum0 += w0;
        }

        float acc[8];
#pragma unroll
        for (int j = 0; j < 8; ++j) acc[j] = acc0[j] + acc1[j];
        float wsum = wsum0 + wsum1;

#pragma unroll
        for (int off = 8; off < 64; off <<= 1) {
#pragma unroll
            for (int j = 0; j < 8; ++j) acc[j] += __shfl_xor(acc[j], off);
            wsum += __shfl_xor(wsum, off);
        }

        if (q == 0) {
            const float inv = 1.0f / wsum;
            float o[8];
#pragma unroll
            for (int j = 0; j < 8; ++j) {
                const float v = acc[j] * inv;
                o[j] = v > 0.f ? v : expm1f(v);
            }
            float* op = &out[(long)node * FDIM + 8 * c];
            *(float4*)op = make_float4(o[0], o[1], o[2], o[3]);
            *(float4*)(op + 4) = make_float4(o[4], o[5], o[6], o[7]);
        }
    }
}

extern "C" void kernel_launch(void* const* d_in, const int* in_sizes, int n_in,
                              void* d_out, int out_size, void* d_ws, size_t ws_size,
                              hipStream_t stream) {
    const float* x = (const float*)d_in[0];
    const float* W = (const float*)d_in[1];
    const float* a = (const float*)d_in[2];
    const int* ei  = (const int*)d_in[3];

    const int N = in_sizes[0] / KDIM;       // 50000
    const int E = in_sizes[3] / 2;          // 1600000
    const int NBU = (N + 63) >> 6;          // 782 buckets of 64 srcs
    const int NBLK = (E + BIN_CHUNK - 1) / BIN_CHUNK;  // 196 bin chunks
    const int GB = (N + 63) / 64;                      // 782 gemm blocks (64 rows)
    const int* srcA = ei;
    const int* dstA = ei + E;

    // workspace layout (all regions 16B aligned; ~16 MB)
    __hip_bfloat16* h_bf = (__hip_bfloat16*)d_ws;          // N*64 bf16
    float* s_src = (float*)(h_bf + (size_t)N * FDIM);      // N
    float* s_dst = s_src + N;                              // N
    int* bcur    = (int*)(s_dst + N);                      // 1024
    u32* pair    = (u32*)(bcur + 1024);                    // NBU*CAP arena
    float* out   = (float*)d_out;

    hipMemsetAsync(bcur, 0, 1024 * sizeof(int), stream);

    gat_bin_kernel<<<dim3(NBLK), dim3(256), 0, stream>>>(
        srcA, dstA, bcur, pair, E, NBU);

    gat_gemm_kernel<<<dim3(GB), dim3(256), 0, stream>>>(
        x, W, a, h_bf, s_src, s_dst, N);

    gat_sortgather_kernel<<<dim3(NBU * 2), dim3(256), 0, stream>>>(
        pair, bcur, s_src, s_dst, h_bf, out, N);
}

// Round 10
// 171.674 us; speedup vs baseline: 1.0372x; 1.0372x over previous
//
#include <hip/hip_runtime.h>
#include <hip/hip_bf16.h>
#include <hip/hip_fp16.h>

// GAT layer on MI355X (gfx950).
//   x: (N=50000, K=256) fp32, W: (K=256, F=64) fp32, a: (1, 128) fp32
//   edge_index: (2, E=1600000) int (src row 0, dst row 1)
// out = elu( segsum_src(e * h[dst]) / segsum_src(e) ),
//   e = exp(-leakyrelu(s_src[src]+s_dst[dst], 0.2)), h = x@W
//
// Round 20: R19 ablation -> per-dispatch overhead ~9us (re-fused bin+gemm;
// R18 3-dispatch structure restored, verified 169.6us). bin+gemm sum ~52
// regardless of fusion; sortgather (50us, VALU 63%, occ 44%, HBM 17%) is
// chain-bound: slds(120cy) -> global(300-400cy) serialized per 16 edges.
// Change: software-pipelined phase B -- prefetch next slds pair before the
// current global loads (branchless, invalid slot -> w=0). Removes the LDS
// leg from the serial chain.

#define ALPHA 0.2f
#define KDIM 256
#define FDIM 64
#define WPAD 8             // bf16 row pad: row stride 264 elems = 528B
#define BIN_CHUNK 8192
#define BUCKET_CAP 4096    // 64-src bucket: mean ~2046 edges; >40 sigma slack
#define HCAP 2304          // 32-src half bucket: mean ~1023; ~40 sigma slack

typedef __bf16 bf16x8 __attribute__((ext_vector_type(8)));
typedef float f32x4 __attribute__((ext_vector_type(4)));
typedef unsigned int u32;
typedef unsigned short u16;

union SmemA {
    struct { int hist[1024]; int lcur[1024]; } bin;   // 8 KB
    __bf16 w[FDIM * (KDIM + WPAD)];                   // 33 KB  w[n][k]
};

// ---------------------------------------------------------------------------
// Kernel A (fused): blocks [0,NBLK) = bin; blocks [NBLK, NBLK+GB) = gemm.
// (byte-identical to round-18 verified version)
// ---------------------------------------------------------------------------
__global__ __launch_bounds__(256) void gat_gemm_bin_kernel(
    const float* __restrict__ x, const float* __restrict__ W,
    const float* __restrict__ a, __hip_bfloat16* __restrict__ h_bf,
    float* __restrict__ s_src, float* __restrict__ s_dst,
    const int* __restrict__ srcA, const int* __restrict__ dstA,
    int* __restrict__ bcur, u32* __restrict__ pair,
    int N, int E, int NBU, int NBLK)
{
    __shared__ SmemA sm;
    const int t = threadIdx.x;

    if ((int)blockIdx.x < NBLK) {
        // ---------------- bin path ----------------
        for (int j = t; j < 1024; j += 256) sm.bin.hist[j] = 0;
        __syncthreads();
        const int base = blockIdx.x * BIN_CHUNK;
        const int cnt = min(BIN_CHUNK, E - base);
        for (int i = t; i < cnt; i += 256)
            atomicAdd(&sm.bin.hist[srcA[base + i] >> 6], 1);
        __syncthreads();
        for (int j = t; j < NBU; j += 256) {
            const int v = sm.bin.hist[j];
            sm.bin.lcur[j] = v ? (j * BUCKET_CAP + atomicAdd(&bcur[j], v)) : 0;
        }
        __syncthreads();
        for (int i = t; i < cnt; i += 256) {
            const int s = srcA[base + i];
            const int d = dstA[base + i];
            const int pos = atomicAdd(&sm.bin.lcur[s >> 6], 1);
            pair[pos] = ((u32)(s & 63) << 16) | (u32)d;   // d < 65536
        }
        return;
    }

    // ---------------- gemm path ----------------
    for (int i = t; i < KDIM * FDIM; i += 256) {
        const int k = i >> 6;
        const int n = i & 63;
        sm.w[n * (KDIM + WPAD) + k] = (__bf16)W[i];
    }
    __syncthreads();

    const int gb = (int)blockIdx.x - NBLK;
    const int lane = t & 63;
    const int wv = t >> 6;              // 0..3
    const int m0 = gb * 64 + wv * 16;   // this wave: rows m0..m0+15
    const int c = lane & 15;
    const int q = lane >> 4;

    const int r0 = m0 + c;
    const float* xp0 = x + (long)(r0 < N ? r0 : N - 1) * KDIM;

    f32x4 acc[4];
#pragma unroll
    for (int ct = 0; ct < 4; ++ct) acc[ct] = (f32x4){0.f, 0.f, 0.f, 0.f};

#pragma unroll 4
    for (int kc = 0; kc < 8; ++kc) {
        const int k0 = kc * 32 + q * 8;
        const float4 xa0 = *(const float4*)(xp0 + k0);
        const float4 xb0 = *(const float4*)(xp0 + k0 + 4);
        bf16x8 af0;
        af0[0] = (__bf16)xa0.x; af0[1] = (__bf16)xa0.y;
        af0[2] = (__bf16)xa0.z; af0[3] = (__bf16)xa0.w;
        af0[4] = (__bf16)xb0.x; af0[5] = (__bf16)xb0.y;
        af0[6] = (__bf16)xb0.z; af0[7] = (__bf16)xb0.w;
#pragma unroll
        for (int ct = 0; ct < 4; ++ct) {
            const bf16x8 bf = *(const bf16x8*)(&sm.w[(ct * 16 + c) * (KDIM + WPAD) + k0]);
            acc[ct] = __builtin_amdgcn_mfma_f32_16x16x32_bf16(af0, bf, acc[ct], 0, 0, 0);
        }
    }

    float a1c[4], a2c[4];
#pragma unroll
    for (int ct = 0; ct < 4; ++ct) {
        a1c[ct] = a[ct * 16 + c];
        a2c[ct] = a[FDIM + ct * 16 + c];
    }

    float s1r[4], s2r[4];
#pragma unroll
    for (int reg = 0; reg < 4; ++reg) {
        float s1 = 0.f, s2 = 0.f;
#pragma unroll
        for (int ct = 0; ct < 4; ++ct) {
            s1 += acc[ct][reg] * a1c[ct];
            s2 += acc[ct][reg] * a2c[ct];
        }
        s1r[reg] = s1; s2r[reg] = s2;
    }
#pragma unroll
    for (int off = 1; off < 16; off <<= 1) {
#pragma unroll
        for (int reg = 0; reg < 4; ++reg) {
            s1r[reg] += __shfl_xor(s1r[reg], off);
            s2r[reg] += __shfl_xor(s2r[reg], off);
        }
    }
#pragma unroll
    for (int reg = 0; reg < 4; ++reg) {
        const int row = m0 + q * 4 + reg;
        if (row < N) {
#pragma unroll
            for (int ct = 0; ct < 4; ++ct)
                h_bf[(long)row * FDIM + ct * 16 + c] = __float2bfloat16(acc[ct][reg]);
            if (c == 0) { s_src[row] = s1r[reg]; s_dst[row] = s2r[reg]; }
        }
    }
}

// ---------------------------------------------------------------------------
// Kernel B (fused sort+gather, half-bucket blocks): 2 blocks (256 thr) per
// 64-src bucket. Phase A unchanged (two-pass count/scan/scatter into slds).
// Phase B: software-pipelined gather -- next iteration's slds pair is
// prefetched before the current global loads issue, so the LDS latency
// hides under the random h-row fetch. Branchless: out-of-range slots
// decode to (d=0, w=0) and contribute nothing.
// ---------------------------------------------------------------------------
__global__ __launch_bounds__(256) void gat_sortgather_kernel(
    const u32* __restrict__ pair, const int* __restrict__ bcur,
    const float* __restrict__ s_src, const float* __restrict__ s_dst,
    const __hip_bfloat16* __restrict__ h_bf, float* __restrict__ out, int N)
{
    __shared__ u32 slds[HCAP];   // 9 KB sorted (dst | f16(wgt)<<16)
    __shared__ int cur[32];
    __shared__ int nst[32];
    __shared__ int nen[32];
    __shared__ float ssl[32];

    const int b = (int)blockIdx.x >> 1;    // bucket
    const int hf = (int)blockIdx.x & 1;    // half: srcs [hf*32, hf*32+32)
    const int t = threadIdx.x;
    const int s0 = (b << 6) + (hf << 5);   // first src of this half
    const int abase = b * BUCKET_CAP;
    const int n = min(bcur[b], BUCKET_CAP);

    if (t < 32) {
        cur[t] = 0;
        ssl[t] = (s0 + t < N) ? s_src[s0 + t] : 0.f;
    }
    __syncthreads();
    // pass 1: count srcs belonging to this half
    for (int i = t; i < n; i += 256) {
        const int sl = (int)(pair[abase + i] >> 16);
        if ((sl >> 5) == hf) atomicAdd(&cur[sl & 31], 1);
    }
    __syncthreads();
    if (t < 32) {   // lanes 0..31 of wave 0: exclusive scan of 32 counts
        const int v = cur[t];
        int incl = v;
#pragma unroll
        for (int off = 1; off < 32; off <<= 1) {
            const int nv = __shfl_up(incl, off);
            if (t >= off) incl += nv;
        }
        const int excl = incl - v;
        nst[t] = excl;
        nen[t] = min(excl + v, HCAP);
        cur[t] = excl;
    }
    __syncthreads();
    // pass 2: scatter matching edges into slds with packed weight
    for (int i = t; i < n; i += 256) {
        const u32 p = pair[abase + i];
        const int sl = (int)(p >> 16);
        if ((sl >> 5) != hf) continue;
        const int d = (int)(p & 0xFFFFu);
        const int slot = atomicAdd(&cur[sl & 31], 1);
        if (slot < HCAP) {
            const float sc = ssl[sl & 31] + s_dst[d];
            const float lr = sc > 0.f ? sc : ALPHA * sc;
            const float wgt = __expf(-lr);
            const u32 wh = (u32)__half_as_ushort(__float2half(wgt));
            slds[slot] = (u32)d | (wh << 16);
        }
    }
    __syncthreads();

    // ---------------- phase B: pipelined gather from LDS edge list --------
    const int wv = t >> 6;       // 0..3
    const int lane = t & 63;
    const int q = lane >> 3;     // edge slot 0..7
    const int c = lane & 7;      // feature octet 0..7
    const __bf16* hb = (const __bf16*)h_bf;

    for (int nl = wv; nl < 32; nl += 4) {
        const int node = s0 + nl;
        if (node >= N) break;
        const int start = nst[nl];
        const int end = nen[nl];

        float acc0[8], acc1[8];
#pragma unroll
        for (int j = 0; j < 8; ++j) { acc0[j] = 0.f; acc1[j] = 0.f; }
        float wsum0 = 0.f, wsum1 = 0.f;

        int e = start + q;
        // prologue: load first pair of stream heads (w=0 when out of range)
        u32 p0 = (e     < end) ? slds[e]     : 0u;
        u32 p1 = (e + 8 < end) ? slds[e + 8] : 0u;
        while (e < end) {
            // prefetch next pair (LDS latency hides under the global loads)
            const u32 n0 = (e + 16 < end) ? slds[e + 16] : 0u;
            const u32 n1 = (e + 24 < end) ? slds[e + 24] : 0u;

            const int d0 = (int)(p0 & 0xFFFFu);
            const int d1 = (int)(p1 & 0xFFFFu);
            const bf16x8 hv0 = *(const bf16x8*)(hb + (long)d0 * FDIM + 8 * c);
            const bf16x8 hv1 = *(const bf16x8*)(hb + (long)d1 * FDIM + 8 * c);
            const float w0 = __half2float(__ushort_as_half((u16)(p0 >> 16)));
            const float w1 = __half2float(__ushort_as_half((u16)(p1 >> 16)));
#pragma unroll
            for (int j = 0; j < 8; ++j) {
                acc0[j] += w0 * (float)hv0[j];
                acc1[j] += w1 * (float)hv1[j];
            }
            wsum0 += w0;
            wsum1 += w1;

            p0 = n0; p1 = n1; e += 16;
        }

        float acc[8];
#pragma unroll
        for (int j = 0; j < 8; ++j) acc[j] = acc0[j] + acc1[j];
        float wsum = wsum0 + wsum1;

#pragma unroll
        for (int off = 8; off < 64; off <<= 1) {
#pragma unroll
            for (int j = 0; j < 8; ++j) acc[j] += __shfl_xor(acc[j], off);
            wsum += __shfl_xor(wsum, off);
        }

        if (q == 0) {
            const float inv = 1.0f / wsum;
            float o[8];
#pragma unroll
            for (int j = 0; j < 8; ++j) {
                const float v = acc[j] * inv;
                o[j] = v > 0.f ? v : expm1f(v);
            }
            float* op = &out[(long)node * FDIM + 8 * c];
            *(float4*)op = make_float4(o[0], o[1], o[2], o[3]);
            *(float4*)(op + 4) = make_float4(o[4], o[5], o[6], o[7]);
        }
    }
}

extern "C" void kernel_launch(void* const* d_in, const int* in_sizes, int n_in,
                              void* d_out, int out_size, void* d_ws, size_t ws_size,
                              hipStream_t stream) {
    const float* x = (const float*)d_in[0];
    const float* W = (const float*)d_in[1];
    const float* a = (const float*)d_in[2];
    const int* ei  = (const int*)d_in[3];

    const int N = in_sizes[0] / KDIM;       // 50000
    const int E = in_sizes[3] / 2;          // 1600000
    const int NBU = (N + 63) >> 6;          // 782 buckets of 64 srcs
    const int NBLK = (E + BIN_CHUNK - 1) / BIN_CHUNK;  // 196 bin chunks
    const int GB = (N + 63) / 64;                      // 782 gemm blocks (64 rows)
    const int* srcA = ei;
    const int* dstA = ei + E;

    // workspace layout (all regions 16B aligned; ~16 MB)
    __hip_bfloat16* h_bf = (__hip_bfloat16*)d_ws;          // N*64 bf16
    float* s_src = (float*)(h_bf + (size_t)N * FDIM);      // N
    float* s_dst = s_src + N;                              // N
    int* bcur    = (int*)(s_dst + N);                      // 1024
    u32* pair    = (u32*)(bcur + 1024);                    // NBU*CAP arena
    float* out   = (float*)d_out;

    hipMemsetAsync(bcur, 0, 1024 * sizeof(int), stream);

    gat_gemm_bin_kernel<<<dim3(NBLK + GB), dim3(256), 0, stream>>>(
        x, W, a, h_bf, s_src, s_dst, srcA, dstA, bcur, pair, N, E, NBU, NBLK);

    gat_sortgather_kernel<<<dim3(NBU * 2), dim3(256), 0, stream>>>(
        pair, bcur, s_src, s_dst, h_bf, out, N);
}